// Round 10
// baseline (126.773 us; speedup 1.0000x reference)
//
#include <hip/hip_runtime.h>
#include <hip/hip_bf16.h>

typedef __attribute__((ext_vector_type(8))) short short8;
typedef __attribute__((ext_vector_type(8))) unsigned short ushort8;
typedef __attribute__((ext_vector_type(4))) float f32x4;

#define NB 2
#define NH 12
#define NL 1024
#define NT 1024
#define ND 64
#define NCH 36
#define DIM 768

// round-to-nearest-even f32 -> bf16 bits (inputs finite; no NaN handling needed)
static __device__ __forceinline__ unsigned short f2bf(float x) {
  union { float f; unsigned int u; } c; c.f = x;
  unsigned int r = c.u + 0x7fffu + ((c.u >> 16) & 1u);
  return (unsigned short)(r >> 16);
}

// ---------------------------------------------------------------------------
// K1: channel-fuse (36 -> 12) + softmax over T, write attn as bf16.
// fuse_b ignored (softmax invariant to a per-row additive constant).
//
// R9 -> R10 (occupancy-as-the-lever): all five load-schedule variants
// (R1..R9) pinned at ~5 B/cyc/CU demand rate, insensitive to L3-vs-HBM
// source and to software pipeline depth -> effective depth/wave ~1-2 is
// compiler/HW-pinned. The one constant: ~13-15 waves/CU. RMSNorm at full
// occupancy streams 9 B/cyc/CU (m146) with the same depth -> rate scales
// with resident waves. This version: 512-thr blocks, 2 t/thread
// (acc[12][2]=24 VGPR, ~40 total -> 8 waves/SIMD eligible), plain float2
// loads, no staging, 768 B LDS. TLP hides latency, not ILP.
// ---------------------------------------------------------------------------
__global__ __launch_bounds__(512) void k_fuse_softmax(
    const float* __restrict__ s0, const float* __restrict__ s1,
    const float* __restrict__ s2, const float* __restrict__ wT,
    unsigned short* __restrict__ attn)
{
  __shared__ float red[2][8][NH];   // [max/sum][wave][head], 768 B
  const int tid = threadIdx.x;
  const int b = blockIdx.x >> 10;
  const int l = blockIdx.x & 1023;
  const int wv = tid >> 6, lane = tid & 63;
  const int t2 = tid * 2;           // each thread owns 2 contiguous t

  float acc[NH][2];
#pragma unroll
  for (int h = 0; h < NH; ++h) { acc[h][0] = 0.f; acc[h][1] = 0.f; }

  const size_t base = (size_t)b * NH * NL * NT + (size_t)l * NT + t2;
  const float* pall[3] = { s0 + base, s1 + base, s2 + base };

#pragma unroll
  for (int g = 0; g < 3; ++g) {
    const float* p = pall[g];
#pragma unroll
    for (int ch = 0; ch < 12; ++ch) {
      const float2 sv = *(const float2*)(p + (size_t)ch * NL * NT);
      const float* wp = wT + (g * 12 + ch) * NH;  // uniform addr
#pragma unroll
      for (int h = 0; h < NH; ++h) {
        const float w = wp[h];
        acc[h][0] = fmaf(w, sv.x, acc[h][0]);
        acc[h][1] = fmaf(w, sv.y, acc[h][1]);
      }
    }
  }

  // --- block-wide max per head (8 waves) ---
  float mx[NH];
#pragma unroll
  for (int h = 0; h < NH; ++h) {
    mx[h] = fmaxf(acc[h][0], acc[h][1]);
#pragma unroll
    for (int off = 32; off > 0; off >>= 1)
      mx[h] = fmaxf(mx[h], __shfl_xor(mx[h], off));
  }
  if (lane == 0) {
#pragma unroll
    for (int h = 0; h < NH; ++h) red[0][wv][h] = mx[h];
  }
  __syncthreads();
#pragma unroll
  for (int h = 0; h < NH; ++h) {
    float m01 = fmaxf(red[0][0][h], red[0][1][h]);
    float m23 = fmaxf(red[0][2][h], red[0][3][h]);
    float m45 = fmaxf(red[0][4][h], red[0][5][h]);
    float m67 = fmaxf(red[0][6][h], red[0][7][h]);
    mx[h] = fmaxf(fmaxf(m01, m23), fmaxf(m45, m67));
  }

  // --- exp + block-wide sum per head ---
  float sm[NH];
#pragma unroll
  for (int h = 0; h < NH; ++h) {
    acc[h][0] = __expf(acc[h][0] - mx[h]);
    acc[h][1] = __expf(acc[h][1] - mx[h]);
    sm[h] = acc[h][0] + acc[h][1];
#pragma unroll
    for (int off = 32; off > 0; off >>= 1)
      sm[h] += __shfl_xor(sm[h], off);
  }
  if (lane == 0) {
#pragma unroll
    for (int h = 0; h < NH; ++h) red[1][wv][h] = sm[h];
  }
  __syncthreads();

#pragma unroll
  for (int h = 0; h < NH; ++h) {
    float s = ((red[1][0][h] + red[1][1][h]) + (red[1][2][h] + red[1][3][h]))
            + ((red[1][4][h] + red[1][5][h]) + (red[1][6][h] + red[1][7][h]));
    const float inv = 1.0f / s;
    unsigned int u = (unsigned int)f2bf(acc[h][0] * inv)
                   | ((unsigned int)f2bf(acc[h][1] * inv) << 16);
    *(unsigned int*)(attn + ((size_t)(b * NH + h) * NL + l) * NT + t2) = u;
  }
}

// ---------------------------------------------------------------------------
// K2a: v (B,H,T,D) f32  ->  vT (B,H,D,T) bf16, via LDS tile transpose.
// Also (block 0 only) writes wT[c][h] = fuse_w[h][c] for K1's SGPR path.
// Runs BEFORE K1.
// ---------------------------------------------------------------------------
__global__ __launch_bounds__(256) void k_transpose_v(
    const float* __restrict__ v, const float* __restrict__ fw,
    unsigned short* __restrict__ vT, float* __restrict__ wT)
{
  __shared__ float vS[128][65];  // +1 pad breaks column-read conflicts
  const int tid = threadIdx.x;
  const int tt = blockIdx.x;   // t-tile of 128
  const int h = blockIdx.y, b = blockIdx.z;
  if (tt == 0 && h == 0 && b == 0) {
    for (int i = tid; i < NCH * NH; i += 256) {   // 432 entries, 256 threads
      int c = i / NH, hh = i % NH;
      wT[c * NH + hh] = fw[hh * NCH + c];
    }
  }
  const int t0 = tt * 128;
  const float* vp = v + ((size_t)(b * NH + h) * NT + t0) * ND;
#pragma unroll
  for (int r = 0; r < 8; ++r) {
    int f = tid + r * 256;            // 2048 float4 chunks
    int t = f >> 4, d4 = (f & 15) * 4;
    float4 x = *(const float4*)(vp + (size_t)t * ND + d4);
    vS[t][d4 + 0] = x.x; vS[t][d4 + 1] = x.y;
    vS[t][d4 + 2] = x.z; vS[t][d4 + 3] = x.w;
  }
  __syncthreads();
  unsigned short* op = vT + (size_t)(b * NH + h) * ND * NT;
#pragma unroll
  for (int r = 0; r < 4; ++r) {
    int c = tid + r * 256;            // 1024 ushort8 chunks
    int d = c >> 4, tl = (c & 15) * 8;
    ushort8 u;
#pragma unroll
    for (int j = 0; j < 8; ++j) u[j] = f2bf(vS[tl + j][d]);
    *(ushort8*)(op + (size_t)d * NT + t0 + tl) = u;
  }
}

// ---------------------------------------------------------------------------
// K2: PV GEMM  x[b,h,l,:] = attn[b,h,l,:] @ v[b,h,:,:]  via bf16 MFMA.
// MFMA 16x16x32 fragment layout (verified passing since R1):
//   A: row = lane&15, k = 8*(lane>>4)+e   (e=0..7, one 16B load)
//   B: col = lane&15, k = 8*(lane>>4)+e   (16B from k-contiguous vT row)
//   C/D: col = lane&15, row = (lane>>4)*4 + reg   [measured m89/m91]
// LDS vS stride 136 ushorts: conflict-free.
// ---------------------------------------------------------------------------
__global__ __launch_bounds__(128) void k_pv(
    const unsigned short* __restrict__ attn,
    const unsigned short* __restrict__ vT,
    unsigned short* __restrict__ xb)
{
  __shared__ unsigned short vS[64][136];
  const int tid = threadIdx.x;
  const int lane = tid & 63, wv = tid >> 6;
  const int lt = blockIdx.x, h = blockIdx.y, b = blockIdx.z;
  const int l0 = lt * 32;
  const unsigned short* ap = attn + ((size_t)(b * NH + h) * NL + l0) * NT;
  const unsigned short* vp = vT + (size_t)(b * NH + h) * ND * NT;
  f32x4 acc[4] = {};
  const int arow = wv * 16 + (lane & 15);
  const int kg = (lane >> 4) * 8;
  const int bn = lane & 15;

  for (int kt = 0; kt < 8; ++kt) {  // k(t)-tiles of 128
    __syncthreads();
#pragma unroll
    for (int r = 0; r < 8; ++r) {   // stage 64 d x 128 t bf16
      int c = tid + r * 128;
      int d = c >> 4, tl = (c & 15) * 8;
      *(ushort8*)&vS[d][tl] = *(const ushort8*)(vp + (size_t)d * NT + kt * 128 + tl);
    }
    __syncthreads();
#pragma unroll
    for (int ks = 0; ks < 4; ++ks) {  // K=32 steps
      short8 af = *(const short8*)(ap + (size_t)arow * NT + kt * 128 + ks * 32 + kg);
#pragma unroll
      for (int dt = 0; dt < 4; ++dt) {
        short8 bf = *(const short8*)&vS[dt * 16 + bn][ks * 32 + kg];
        acc[dt] = __builtin_amdgcn_mfma_f32_16x16x32_bf16(af, bf, acc[dt], 0, 0, 0);
      }
    }
  }
  // write x as bf16 in (B, L, H*D) layout so proj's A is k-contiguous
  const int crow0 = wv * 16 + (lane >> 4) * 4;
#pragma unroll
  for (int dt = 0; dt < 4; ++dt) {
#pragma unroll
    for (int r = 0; r < 4; ++r) {
      int row = l0 + crow0 + r;
      xb[((size_t)b * NL + row) * DIM + h * ND + dt * 16 + bn] = f2bf(acc[dt][r]);
    }
  }
}

// ---------------------------------------------------------------------------
// K3: out[n,o] = sum_k x[n,k] * proj_w[o,k] + proj_b[o], bf16 MFMA, f32 out.
// proj_w is [o][k] row-major == B^T, so B-fragment needs no transpose.
// ---------------------------------------------------------------------------
__global__ __launch_bounds__(256) void k_proj(
    const unsigned short* __restrict__ xb, const float* __restrict__ pw,
    const float* __restrict__ pb, float* __restrict__ out)
{
  __shared__ unsigned short wS[64][136];
  const int tid = threadIdx.x;
  const int lane = tid & 63, wv = tid >> 6;
  const int n0 = blockIdx.x * 64, o0 = blockIdx.y * 64;
  f32x4 acc[4] = {};
  const int kg = (lane >> 4) * 8;
  const int bn = lane & 15;
  const int arow = n0 + wv * 16 + bn;

  for (int kt = 0; kt < 6; ++kt) {  // k-tiles of 128 (768 total)
    __syncthreads();
#pragma unroll
    for (int r = 0; r < 4; ++r) {   // stage W tile 64 o x 128 k as bf16
      int c = tid + r * 256;
      int oi = c >> 4, kl = (c & 15) * 8;
      const float* wp = pw + (size_t)(o0 + oi) * DIM + kt * 128 + kl;
      float4 x0 = *(const float4*)(wp);
      float4 x1 = *(const float4*)(wp + 4);
      ushort8 u;
      u[0] = f2bf(x0.x); u[1] = f2bf(x0.y); u[2] = f2bf(x0.z); u[3] = f2bf(x0.w);
      u[4] = f2bf(x1.x); u[5] = f2bf(x1.y); u[6] = f2bf(x1.z); u[7] = f2bf(x1.w);
      *(ushort8*)&wS[oi][kl] = u;
    }
    __syncthreads();
#pragma unroll
    for (int ks = 0; ks < 4; ++ks) {
      short8 af = *(const short8*)(xb + (size_t)arow * DIM + kt * 128 + ks * 32 + kg);
#pragma unroll
      for (int ot = 0; ot < 4; ++ot) {
        short8 bf = *(const short8*)&wS[ot * 16 + bn][ks * 32 + kg];
        acc[ot] = __builtin_amdgcn_mfma_f32_16x16x32_bf16(af, bf, acc[ot], 0, 0, 0);
      }
    }
  }
  const int crow0 = wv * 16 + (lane >> 4) * 4;
#pragma unroll
  for (int ot = 0; ot < 4; ++ot) {
    const int oc = o0 + ot * 16 + bn;
    const float bias = pb[oc];
#pragma unroll
    for (int r = 0; r < 4; ++r) {
      int row = n0 + crow0 + r;
      out[(size_t)row * DIM + oc] = acc[ot][r] + bias;
    }
  }
}

extern "C" void kernel_launch(void* const* d_in, const int* in_sizes, int n_in,
                              void* d_out, int out_size, void* d_ws, size_t ws_size,
                              hipStream_t stream) {
  const float* s0 = (const float*)d_in[0];
  const float* s1 = (const float*)d_in[1];
  const float* s2 = (const float*)d_in[2];
  const float* v  = (const float*)d_in[3];
  const float* fw = (const float*)d_in[4];
  // d_in[5] = fuse_b: unused — softmax is invariant to a per-row additive bias
  const float* pw = (const float*)d_in[6];
  const float* pb = (const float*)d_in[7];
  float* out = (float*)d_out;

  // workspace layout (bytes):
  //   attn bf16 50,331,648 | vT bf16 3,145,728 | xb bf16 3,145,728 | wT f32 1,728
  const size_t attn_bytes = (size_t)NB * NH * NL * NT * 2;
  const size_t vT_bytes   = (size_t)NB * NH * ND * NT * 2;
  const size_t xb_bytes   = (size_t)NB * NL * DIM * 2;
  unsigned short* attn = (unsigned short*)d_ws;
  unsigned short* vT   = (unsigned short*)((char*)d_ws + attn_bytes);
  unsigned short* xb   = (unsigned short*)((char*)d_ws + attn_bytes + vT_bytes);
  float*          wT   = (float*)((char*)d_ws + attn_bytes + vT_bytes + xb_bytes);

  // k_transpose_v first: it also produces wT, which K1 consumes.
  k_transpose_v<<<dim3(8, NH, NB), dim3(256), 0, stream>>>(v, fw, vT, wT);
  k_fuse_softmax<<<dim3(NB * NL), dim3(512), 0, stream>>>(s0, s1, s2, wT, attn);
  k_pv<<<dim3(32, NH, NB), dim3(128), 0, stream>>>(attn, vT, xb);
  k_proj<<<dim3(32, DIM / 64), dim3(256), 0, stream>>>(xb, pw, pb, out);
}

// Round 11
// 112.386 us; speedup vs baseline: 1.1280x; 1.1280x over previous
//
#include <hip/hip_runtime.h>
#include <hip/hip_bf16.h>

typedef __attribute__((ext_vector_type(8))) short short8;
typedef __attribute__((ext_vector_type(8))) unsigned short ushort8;
typedef __attribute__((ext_vector_type(4))) unsigned short u16x4;  // NOT "ushort4": HIP predefines that type
typedef __attribute__((ext_vector_type(4))) float f32x4;

#define NB 2
#define NH 12
#define NL 1024
#define NT 1024
#define ND 64
#define NCH 36
#define DIM 768

// round-to-nearest-even f32 -> bf16 bits (inputs finite; no NaN handling needed)
static __device__ __forceinline__ unsigned short f2bf(float x) {
  union { float f; unsigned int u; } c; c.f = x;
  unsigned int r = c.u + 0x7fffu + ((c.u >> 16) & 1u);
  return (unsigned short)(r >> 16);
}

// ---------------------------------------------------------------------------
// K1: channel-fuse (36 -> 12) + softmax over T, write attn as bf16.
// One block per (b, l). fuse_b ignored (softmax invariant to per-row const).
//
// R10 -> R11: six structurally distinct K1s (plain, reg-pipe, DMA x2, DMA x4,
// burst-shaped, high-occupancy) all pinned at ~5 B/cyc/CU; occupancy itself
// refuses to exceed ~41-46% regardless of resources; counted-vmcnt DMA gave
// effective depth ~1. Remaining hypothesis is address-level (36 gather
// streams differ only above bit 22 -> same cache-set/MSHR bits), which no
// schedule can fix. So: revert to the fastest measured structure (R3/R5,
// 121 us), make it self-contained (weights via in-block LDS transpose), and
// add NON-TEMPORAL loads for the once-read scores (nt: no-allocate,
// frees L3 for attn/vT which are re-read; also a clean diagnostic -
// FETCH_SIZE should rise to ~300 MB).
// ---------------------------------------------------------------------------
__global__ __launch_bounds__(256) void k_fuse_softmax(
    const float* __restrict__ s0, const float* __restrict__ s1,
    const float* __restrict__ s2, const float* __restrict__ fw,
    unsigned short* __restrict__ attn)
{
  __shared__ float wS[NCH][16];     // wS[c][h] = fuse_w[h][c]; row padded to 64B
  __shared__ float red[2][4][NH];   // [max/sum][wave][head]
  const int tid = threadIdx.x;
  const int b = blockIdx.x >> 10;
  const int l = blockIdx.x & 1023;
  const int wv = tid >> 6, lane = tid & 63;

  for (int i = tid; i < NCH * NH; i += 256) {   // 432 entries, strided
    int c = i / NH, h = i % NH;
    wS[c][h] = fw[h * NCH + c];
  }
  __syncthreads();

  float acc[NH][4];
#pragma unroll
  for (int h = 0; h < NH; ++h) {
    acc[h][0] = 0.f; acc[h][1] = 0.f; acc[h][2] = 0.f; acc[h][3] = 0.f;
  }

  const int t0 = tid * 4;  // each thread owns 4 contiguous t
  const size_t base = (size_t)b * NH * NL * NT + (size_t)l * NT + t0;
  const float* ps[3] = { s0 + base, s1 + base, s2 + base };
#pragma unroll
  for (int g = 0; g < 3; ++g) {
    const float* p = ps[g];
#pragma unroll
    for (int ch = 0; ch < NH; ++ch) {
      // scores are read exactly once -> non-temporal (nt) streaming load
      const f32x4 sv =
          __builtin_nontemporal_load((const f32x4*)(p + (size_t)ch * NL * NT));
#pragma unroll
      for (int h = 0; h < NH; ++h) {
        const float w = wS[g * NH + ch][h];  // uniform LDS read -> broadcast
        acc[h][0] = fmaf(w, sv[0], acc[h][0]);
        acc[h][1] = fmaf(w, sv[1], acc[h][1]);
        acc[h][2] = fmaf(w, sv[2], acc[h][2]);
        acc[h][3] = fmaf(w, sv[3], acc[h][3]);
      }
    }
  }

  // --- block-wide max per head (in registers) ---
  float mx[NH];
#pragma unroll
  for (int h = 0; h < NH; ++h) {
    mx[h] = fmaxf(fmaxf(acc[h][0], acc[h][1]), fmaxf(acc[h][2], acc[h][3]));
#pragma unroll
    for (int off = 32; off > 0; off >>= 1)
      mx[h] = fmaxf(mx[h], __shfl_xor(mx[h], off));
  }
  if (lane == 0) {
#pragma unroll
    for (int h = 0; h < NH; ++h) red[0][wv][h] = mx[h];
  }
  __syncthreads();
#pragma unroll
  for (int h = 0; h < NH; ++h)
    mx[h] = fmaxf(fmaxf(red[0][0][h], red[0][1][h]),
                  fmaxf(red[0][2][h], red[0][3][h]));

  // --- exp + block-wide sum per head ---
  float sm[NH];
#pragma unroll
  for (int h = 0; h < NH; ++h) {
    acc[h][0] = __expf(acc[h][0] - mx[h]);
    acc[h][1] = __expf(acc[h][1] - mx[h]);
    acc[h][2] = __expf(acc[h][2] - mx[h]);
    acc[h][3] = __expf(acc[h][3] - mx[h]);
    sm[h] = (acc[h][0] + acc[h][1]) + (acc[h][2] + acc[h][3]);
#pragma unroll
    for (int off = 32; off > 0; off >>= 1)
      sm[h] += __shfl_xor(sm[h], off);
  }
  if (lane == 0) {
#pragma unroll
    for (int h = 0; h < NH; ++h) red[1][wv][h] = sm[h];
  }
  __syncthreads();

#pragma unroll
  for (int h = 0; h < NH; ++h) {
    float s = (red[1][0][h] + red[1][1][h]) + (red[1][2][h] + red[1][3][h]);
    float inv = 1.0f / s;
    u16x4 u;
    u[0] = f2bf(acc[h][0] * inv);
    u[1] = f2bf(acc[h][1] * inv);
    u[2] = f2bf(acc[h][2] * inv);
    u[3] = f2bf(acc[h][3] * inv);
    *(u16x4*)(attn + ((size_t)(b * NH + h) * NL + l) * NT + t0) = u;
  }
}

// ---------------------------------------------------------------------------
// K2a: v (B,H,T,D) f32  ->  vT (B,H,D,T) bf16, via LDS tile transpose.
// (wT side-job removed in R11: K1 builds its weight LDS in-block.)
// ---------------------------------------------------------------------------
__global__ __launch_bounds__(256) void k_transpose_v(
    const float* __restrict__ v, unsigned short* __restrict__ vT)
{
  __shared__ float vS[128][65];  // +1 pad breaks column-read conflicts
  const int tid = threadIdx.x;
  const int tt = blockIdx.x;   // t-tile of 128
  const int h = blockIdx.y, b = blockIdx.z;
  const int t0 = tt * 128;
  const float* vp = v + ((size_t)(b * NH + h) * NT + t0) * ND;
#pragma unroll
  for (int r = 0; r < 8; ++r) {
    int f = tid + r * 256;            // 2048 float4 chunks
    int t = f >> 4, d4 = (f & 15) * 4;
    float4 x = *(const float4*)(vp + (size_t)t * ND + d4);
    vS[t][d4 + 0] = x.x; vS[t][d4 + 1] = x.y;
    vS[t][d4 + 2] = x.z; vS[t][d4 + 3] = x.w;
  }
  __syncthreads();
  unsigned short* op = vT + (size_t)(b * NH + h) * ND * NT;
#pragma unroll
  for (int r = 0; r < 4; ++r) {
    int c = tid + r * 256;            // 1024 ushort8 chunks
    int d = c >> 4, tl = (c & 15) * 8;
    ushort8 u;
#pragma unroll
    for (int j = 0; j < 8; ++j) u[j] = f2bf(vS[tl + j][d]);
    *(ushort8*)(op + (size_t)d * NT + t0 + tl) = u;
  }
}

// ---------------------------------------------------------------------------
// K2: PV GEMM  x[b,h,l,:] = attn[b,h,l,:] @ v[b,h,:,:]  via bf16 MFMA.
// MFMA 16x16x32 fragment layout (verified passing since R1):
//   A: row = lane&15, k = 8*(lane>>4)+e   (e=0..7, one 16B load)
//   B: col = lane&15, k = 8*(lane>>4)+e   (16B from k-contiguous vT row)
//   C/D: col = lane&15, row = (lane>>4)*4 + reg   [measured m89/m91]
// LDS vS stride 136 ushorts: conflict-free.
// ---------------------------------------------------------------------------
__global__ __launch_bounds__(128) void k_pv(
    const unsigned short* __restrict__ attn,
    const unsigned short* __restrict__ vT,
    unsigned short* __restrict__ xb)
{
  __shared__ unsigned short vS[64][136];
  const int tid = threadIdx.x;
  const int lane = tid & 63, wv = tid >> 6;
  const int lt = blockIdx.x, h = blockIdx.y, b = blockIdx.z;
  const int l0 = lt * 32;
  const unsigned short* ap = attn + ((size_t)(b * NH + h) * NL + l0) * NT;
  const unsigned short* vp = vT + (size_t)(b * NH + h) * ND * NT;
  f32x4 acc[4] = {};
  const int arow = wv * 16 + (lane & 15);
  const int kg = (lane >> 4) * 8;
  const int bn = lane & 15;

  for (int kt = 0; kt < 8; ++kt) {  // k(t)-tiles of 128
    __syncthreads();
#pragma unroll
    for (int r = 0; r < 8; ++r) {   // stage 64 d x 128 t bf16
      int c = tid + r * 128;
      int d = c >> 4, tl = (c & 15) * 8;
      *(ushort8*)&vS[d][tl] = *(const ushort8*)(vp + (size_t)d * NT + kt * 128 + tl);
    }
    __syncthreads();
#pragma unroll
    for (int ks = 0; ks < 4; ++ks) {  // K=32 steps
      short8 af = *(const short8*)(ap + (size_t)arow * NT + kt * 128 + ks * 32 + kg);
#pragma unroll
      for (int dt = 0; dt < 4; ++dt) {
        short8 bf = *(const short8*)&vS[dt * 16 + bn][ks * 32 + kg];
        acc[dt] = __builtin_amdgcn_mfma_f32_16x16x32_bf16(af, bf, acc[dt], 0, 0, 0);
      }
    }
  }
  // write x as bf16 in (B, L, H*D) layout so proj's A is k-contiguous
  const int crow0 = wv * 16 + (lane >> 4) * 4;
#pragma unroll
  for (int dt = 0; dt < 4; ++dt) {
#pragma unroll
    for (int r = 0; r < 4; ++r) {
      int row = l0 + crow0 + r;
      xb[((size_t)b * NL + row) * DIM + h * ND + dt * 16 + bn] = f2bf(acc[dt][r]);
    }
  }
}

// ---------------------------------------------------------------------------
// K3: out[n,o] = sum_k x[n,k] * proj_w[o,k] + proj_b[o], bf16 MFMA, f32 out.
// proj_w is [o][k] row-major == B^T, so B-fragment needs no transpose.
// ---------------------------------------------------------------------------
__global__ __launch_bounds__(256) void k_proj(
    const unsigned short* __restrict__ xb, const float* __restrict__ pw,
    const float* __restrict__ pb, float* __restrict__ out)
{
  __shared__ unsigned short wS[64][136];
  const int tid = threadIdx.x;
  const int lane = tid & 63, wv = tid >> 6;
  const int n0 = blockIdx.x * 64, o0 = blockIdx.y * 64;
  f32x4 acc[4] = {};
  const int kg = (lane >> 4) * 8;
  const int bn = lane & 15;
  const int arow = n0 + wv * 16 + bn;

  for (int kt = 0; kt < 6; ++kt) {  // k-tiles of 128 (768 total)
    __syncthreads();
#pragma unroll
    for (int r = 0; r < 4; ++r) {   // stage W tile 64 o x 128 k as bf16
      int c = tid + r * 256;
      int oi = c >> 4, kl = (c & 15) * 8;
      const float* wp = pw + (size_t)(o0 + oi) * DIM + kt * 128 + kl;
      float4 x0 = *(const float4*)(wp);
      float4 x1 = *(const float4*)(wp + 4);
      ushort8 u;
      u[0] = f2bf(x0.x); u[1] = f2bf(x0.y); u[2] = f2bf(x0.z); u[3] = f2bf(x0.w);
      u[4] = f2bf(x1.x); u[5] = f2bf(x1.y); u[6] = f2bf(x1.z); u[7] = f2bf(x1.w);
      *(ushort8*)&wS[oi][kl] = u;
    }
    __syncthreads();
#pragma unroll
    for (int ks = 0; ks < 4; ++ks) {
      short8 af = *(const short8*)(xb + (size_t)arow * DIM + kt * 128 + ks * 32 + kg);
#pragma unroll
      for (int ot = 0; ot < 4; ++ot) {
        short8 bf = *(const short8*)&wS[ot * 16 + bn][ks * 32 + kg];
        acc[ot] = __builtin_amdgcn_mfma_f32_16x16x32_bf16(af, bf, acc[ot], 0, 0, 0);
      }
    }
  }
  const int crow0 = wv * 16 + (lane >> 4) * 4;
#pragma unroll
  for (int ot = 0; ot < 4; ++ot) {
    const int oc = o0 + ot * 16 + bn;
    const float bias = pb[oc];
#pragma unroll
    for (int r = 0; r < 4; ++r) {
      int row = n0 + crow0 + r;
      out[(size_t)row * DIM + oc] = acc[ot][r] + bias;
    }
  }
}

extern "C" void kernel_launch(void* const* d_in, const int* in_sizes, int n_in,
                              void* d_out, int out_size, void* d_ws, size_t ws_size,
                              hipStream_t stream) {
  const float* s0 = (const float*)d_in[0];
  const float* s1 = (const float*)d_in[1];
  const float* s2 = (const float*)d_in[2];
  const float* v  = (const float*)d_in[3];
  const float* fw = (const float*)d_in[4];
  // d_in[5] = fuse_b: unused — softmax is invariant to a per-row additive bias
  const float* pw = (const float*)d_in[6];
  const float* pb = (const float*)d_in[7];
  float* out = (float*)d_out;

  // workspace layout (bytes): attn bf16 50,331,648 | vT bf16 3,145,728 | xb bf16 3,145,728
  const size_t attn_bytes = (size_t)NB * NH * NL * NT * 2;
  const size_t vT_bytes   = (size_t)NB * NH * ND * NT * 2;
  unsigned short* attn = (unsigned short*)d_ws;
  unsigned short* vT   = (unsigned short*)((char*)d_ws + attn_bytes);
  unsigned short* xb   = (unsigned short*)((char*)d_ws + attn_bytes + vT_bytes);

  k_transpose_v<<<dim3(8, NH, NB), dim3(256), 0, stream>>>(v, vT);
  k_fuse_softmax<<<dim3(NB * NL), dim3(256), 0, stream>>>(s0, s1, s2, fw, attn);
  k_pv<<<dim3(32, NH, NB), dim3(128), 0, stream>>>(attn, vT, xb);
  k_proj<<<dim3(32, DIM / 64), dim3(256), 0, stream>>>(xb, pw, pb, out);
}

// Round 12
// 111.094 us; speedup vs baseline: 1.1411x; 1.0116x over previous
//
#include <hip/hip_runtime.h>
#include <hip/hip_bf16.h>

typedef __attribute__((ext_vector_type(8))) short short8;
typedef __attribute__((ext_vector_type(8))) unsigned short ushort8;
typedef __attribute__((ext_vector_type(4))) unsigned short u16x4;  // NOT "ushort4": HIP predefines that type
typedef __attribute__((ext_vector_type(4))) float f32x4;

#define NB 2
#define NH 12
#define NL 1024
#define NT 1024
#define ND 64
#define NCH 36
#define DIM 768

// round-to-nearest-even f32 -> bf16 bits (inputs finite; no NaN handling needed)
static __device__ __forceinline__ unsigned short f2bf(float x) {
  union { float f; unsigned int u; } c; c.f = x;
  unsigned int r = c.u + 0x7fffu + ((c.u >> 16) & 1u);
  return (unsigned short)(r >> 16);
}

// ---------------------------------------------------------------------------
// K1: channel-fuse (36 -> 12) + softmax over T, write attn as bf16.
// fuse_b ignored (softmax invariant to a per-row additive constant).
//
// R11 -> R12: nt loads were the R11 win (121 -> 87.5 us): the bottleneck was
// the cache-allocation path. R8's burst-shape test was masked by that path;
// retest it under nt: 512-thread blocks over 2 ADJACENT rows (8 KB
// contiguous per plane per block instead of 4 KB) -> halves the per-byte
// stream-switch rate at the HBM controllers. Wave (r,q): row r=wv>>2,
// quarter q=wv&3. Per-row softmax reduction across 4 waves.
// ---------------------------------------------------------------------------
__global__ __launch_bounds__(512) void k_fuse_softmax(
    const float* __restrict__ s0, const float* __restrict__ s1,
    const float* __restrict__ s2, const float* __restrict__ fw,
    unsigned short* __restrict__ attn)
{
  __shared__ float wS[NCH][16];      // wS[c][h] = fuse_w[h][c]; row padded 64B
  __shared__ float red[2][2][4][NH]; // [max/sum][row][q-wave][head]
  const int tid = threadIdx.x;
  const int wv = tid >> 6, lane = tid & 63;
  const int r = wv >> 2, q = wv & 3; // row-within-pair, quarter-within-row
  const int b = blockIdx.x >> 9;
  const int l = ((blockIdx.x & 511) << 1) | r;
  const int t0 = q * 256 + lane * 4; // within-row t offset

  for (int i = tid; i < NCH * NH; i += 512) {
    int c = i / NH, h = i % NH;
    wS[c][h] = fw[h * NCH + c];
  }
  __syncthreads();

  float acc[NH][4];
#pragma unroll
  for (int h = 0; h < NH; ++h) {
    acc[h][0] = 0.f; acc[h][1] = 0.f; acc[h][2] = 0.f; acc[h][3] = 0.f;
  }

  const size_t base = (size_t)b * NH * NL * NT + (size_t)l * NT + t0;
  const float* ps[3] = { s0 + base, s1 + base, s2 + base };
#pragma unroll
  for (int g = 0; g < 3; ++g) {
    const float* p = ps[g];
#pragma unroll
    for (int ch = 0; ch < NH; ++ch) {
      // scores read exactly once -> non-temporal streaming load
      const f32x4 sv =
          __builtin_nontemporal_load((const f32x4*)(p + (size_t)ch * NL * NT));
#pragma unroll
      for (int h = 0; h < NH; ++h) {
        const float w = wS[g * NH + ch][h];  // uniform LDS read -> broadcast
        acc[h][0] = fmaf(w, sv[0], acc[h][0]);
        acc[h][1] = fmaf(w, sv[1], acc[h][1]);
        acc[h][2] = fmaf(w, sv[2], acc[h][2]);
        acc[h][3] = fmaf(w, sv[3], acc[h][3]);
      }
    }
  }

  // --- per-row max per head (4 q-waves) ---
  float mx[NH];
#pragma unroll
  for (int h = 0; h < NH; ++h) {
    mx[h] = fmaxf(fmaxf(acc[h][0], acc[h][1]), fmaxf(acc[h][2], acc[h][3]));
#pragma unroll
    for (int off = 32; off > 0; off >>= 1)
      mx[h] = fmaxf(mx[h], __shfl_xor(mx[h], off));
  }
  if (lane == 0) {
#pragma unroll
    for (int h = 0; h < NH; ++h) red[0][r][q][h] = mx[h];
  }
  __syncthreads();
#pragma unroll
  for (int h = 0; h < NH; ++h)
    mx[h] = fmaxf(fmaxf(red[0][r][0][h], red[0][r][1][h]),
                  fmaxf(red[0][r][2][h], red[0][r][3][h]));

  // --- exp + per-row sum per head ---
  float sm[NH];
#pragma unroll
  for (int h = 0; h < NH; ++h) {
    acc[h][0] = __expf(acc[h][0] - mx[h]);
    acc[h][1] = __expf(acc[h][1] - mx[h]);
    acc[h][2] = __expf(acc[h][2] - mx[h]);
    acc[h][3] = __expf(acc[h][3] - mx[h]);
    sm[h] = (acc[h][0] + acc[h][1]) + (acc[h][2] + acc[h][3]);
#pragma unroll
    for (int off = 32; off > 0; off >>= 1)
      sm[h] += __shfl_xor(sm[h], off);
  }
  if (lane == 0) {
#pragma unroll
    for (int h = 0; h < NH; ++h) red[1][r][q][h] = sm[h];
  }
  __syncthreads();

#pragma unroll
  for (int h = 0; h < NH; ++h) {
    float s = (red[1][r][0][h] + red[1][r][1][h]) +
              (red[1][r][2][h] + red[1][r][3][h]);
    float inv = 1.0f / s;
    u16x4 u;
    u[0] = f2bf(acc[h][0] * inv);
    u[1] = f2bf(acc[h][1] * inv);
    u[2] = f2bf(acc[h][2] * inv);
    u[3] = f2bf(acc[h][3] * inv);
    *(u16x4*)(attn + ((size_t)(b * NH + h) * NL + l) * NT + t0) = u;
  }
}

// ---------------------------------------------------------------------------
// K2a: v (B,H,T,D) f32  ->  vT (B,H,D,T) bf16, via LDS tile transpose.
// v is read exactly once -> nt loads.
// ---------------------------------------------------------------------------
__global__ __launch_bounds__(256) void k_transpose_v(
    const float* __restrict__ v, unsigned short* __restrict__ vT)
{
  __shared__ float vS[128][65];  // +1 pad breaks column-read conflicts
  const int tid = threadIdx.x;
  const int tt = blockIdx.x;   // t-tile of 128
  const int h = blockIdx.y, b = blockIdx.z;
  const int t0 = tt * 128;
  const float* vp = v + ((size_t)(b * NH + h) * NT + t0) * ND;
#pragma unroll
  for (int r = 0; r < 8; ++r) {
    int f = tid + r * 256;            // 2048 float4 chunks
    int t = f >> 4, d4 = (f & 15) * 4;
    f32x4 x = __builtin_nontemporal_load((const f32x4*)(vp + (size_t)t * ND + d4));
    vS[t][d4 + 0] = x[0]; vS[t][d4 + 1] = x[1];
    vS[t][d4 + 2] = x[2]; vS[t][d4 + 3] = x[3];
  }
  __syncthreads();
  unsigned short* op = vT + (size_t)(b * NH + h) * ND * NT;
#pragma unroll
  for (int r = 0; r < 4; ++r) {
    int c = tid + r * 256;            // 1024 ushort8 chunks
    int d = c >> 4, tl = (c & 15) * 8;
    ushort8 u;
#pragma unroll
    for (int j = 0; j < 8; ++j) u[j] = f2bf(vS[tl + j][d]);
    *(ushort8*)(op + (size_t)d * NT + t0 + tl) = u;
  }
}

// ---------------------------------------------------------------------------
// K2: PV GEMM  x[b,h,l,:] = attn[b,h,l,:] @ v[b,h,:,:]  via bf16 MFMA.
// attn read exactly once -> nt (keeps L2/L3 for vT, which is re-read 32x).
// MFMA 16x16x32 fragment layout (verified passing since R1):
//   A: row = lane&15, k = 8*(lane>>4)+e ; B: col = lane&15, same k
//   C/D: col = lane&15, row = (lane>>4)*4 + reg   [measured m89/m91]
// LDS vS stride 136 ushorts: conflict-free.
// ---------------------------------------------------------------------------
__global__ __launch_bounds__(128) void k_pv(
    const unsigned short* __restrict__ attn,
    const unsigned short* __restrict__ vT,
    unsigned short* __restrict__ xb)
{
  __shared__ unsigned short vS[64][136];
  const int tid = threadIdx.x;
  const int lane = tid & 63, wv = tid >> 6;
  const int lt = blockIdx.x, h = blockIdx.y, b = blockIdx.z;
  const int l0 = lt * 32;
  const unsigned short* ap = attn + ((size_t)(b * NH + h) * NL + l0) * NT;
  const unsigned short* vp = vT + (size_t)(b * NH + h) * ND * NT;
  f32x4 acc[4] = {};
  const int arow = wv * 16 + (lane & 15);
  const int kg = (lane >> 4) * 8;
  const int bn = lane & 15;

  for (int kt = 0; kt < 8; ++kt) {  // k(t)-tiles of 128
    __syncthreads();
#pragma unroll
    for (int r = 0; r < 8; ++r) {   // stage 64 d x 128 t bf16
      int c = tid + r * 128;
      int d = c >> 4, tl = (c & 15) * 8;
      *(ushort8*)&vS[d][tl] = *(const ushort8*)(vp + (size_t)d * NT + kt * 128 + tl);
    }
    __syncthreads();
#pragma unroll
    for (int ks = 0; ks < 4; ++ks) {  // K=32 steps
      short8 af = __builtin_nontemporal_load(
          (const short8*)(ap + (size_t)arow * NT + kt * 128 + ks * 32 + kg));
#pragma unroll
      for (int dt = 0; dt < 4; ++dt) {
        short8 bf = *(const short8*)&vS[dt * 16 + bn][ks * 32 + kg];
        acc[dt] = __builtin_amdgcn_mfma_f32_16x16x32_bf16(af, bf, acc[dt], 0, 0, 0);
      }
    }
  }
  // write x as bf16 in (B, L, H*D) layout so proj's A is k-contiguous
  const int crow0 = wv * 16 + (lane >> 4) * 4;
#pragma unroll
  for (int dt = 0; dt < 4; ++dt) {
#pragma unroll
    for (int r = 0; r < 4; ++r) {
      int row = l0 + crow0 + r;
      xb[((size_t)b * NL + row) * DIM + h * ND + dt * 16 + bn] = f2bf(acc[dt][r]);
    }
  }
}

// ---------------------------------------------------------------------------
// K3: out[n,o] = sum_k x[n,k] * proj_w[o,k] + proj_b[o], bf16 MFMA, f32 out.
// proj_w is [o][k] row-major == B^T, so B-fragment needs no transpose.
// ---------------------------------------------------------------------------
__global__ __launch_bounds__(256) void k_proj(
    const unsigned short* __restrict__ xb, const float* __restrict__ pw,
    const float* __restrict__ pb, float* __restrict__ out)
{
  __shared__ unsigned short wS[64][136];
  const int tid = threadIdx.x;
  const int lane = tid & 63, wv = tid >> 6;
  const int n0 = blockIdx.x * 64, o0 = blockIdx.y * 64;
  f32x4 acc[4] = {};
  const int kg = (lane >> 4) * 8;
  const int bn = lane & 15;
  const int arow = n0 + wv * 16 + bn;

  for (int kt = 0; kt < 6; ++kt) {  // k-tiles of 128 (768 total)
    __syncthreads();
#pragma unroll
    for (int r = 0; r < 4; ++r) {   // stage W tile 64 o x 128 k as bf16
      int c = tid + r * 256;
      int oi = c >> 4, kl = (c & 15) * 8;
      const float* wp = pw + (size_t)(o0 + oi) * DIM + kt * 128 + kl;
      float4 x0 = *(const float4*)(wp);
      float4 x1 = *(const float4*)(wp + 4);
      ushort8 u;
      u[0] = f2bf(x0.x); u[1] = f2bf(x0.y); u[2] = f2bf(x0.z); u[3] = f2bf(x0.w);
      u[4] = f2bf(x1.x); u[5] = f2bf(x1.y); u[6] = f2bf(x1.z); u[7] = f2bf(x1.w);
      *(ushort8*)&wS[oi][kl] = u;
    }
    __syncthreads();
#pragma unroll
    for (int ks = 0; ks < 4; ++ks) {
      short8 af = *(const short8*)(xb + (size_t)arow * DIM + kt * 128 + ks * 32 + kg);
#pragma unroll
      for (int ot = 0; ot < 4; ++ot) {
        short8 bf = *(const short8*)&wS[ot * 16 + bn][ks * 32 + kg];
        acc[ot] = __builtin_amdgcn_mfma_f32_16x16x32_bf16(af, bf, acc[ot], 0, 0, 0);
      }
    }
  }
  const int crow0 = wv * 16 + (lane >> 4) * 4;
#pragma unroll
  for (int ot = 0; ot < 4; ++ot) {
    const int oc = o0 + ot * 16 + bn;
    const float bias = pb[oc];
#pragma unroll
    for (int r = 0; r < 4; ++r) {
      int row = n0 + crow0 + r;
      out[(size_t)row * DIM + oc] = acc[ot][r] + bias;
    }
  }
}

extern "C" void kernel_launch(void* const* d_in, const int* in_sizes, int n_in,
                              void* d_out, int out_size, void* d_ws, size_t ws_size,
                              hipStream_t stream) {
  const float* s0 = (const float*)d_in[0];
  const float* s1 = (const float*)d_in[1];
  const float* s2 = (const float*)d_in[2];
  const float* v  = (const float*)d_in[3];
  const float* fw = (const float*)d_in[4];
  // d_in[5] = fuse_b: unused — softmax is invariant to a per-row additive bias
  const float* pw = (const float*)d_in[6];
  const float* pb = (const float*)d_in[7];
  float* out = (float*)d_out;

  // workspace layout (bytes): attn bf16 50,331,648 | vT bf16 3,145,728 | xb bf16 3,145,728
  const size_t attn_bytes = (size_t)NB * NH * NL * NT * 2;
  const size_t vT_bytes   = (size_t)NB * NH * ND * NT * 2;
  unsigned short* attn = (unsigned short*)d_ws;
  unsigned short* vT   = (unsigned short*)((char*)d_ws + attn_bytes);
  unsigned short* xb   = (unsigned short*)((char*)d_ws + attn_bytes + vT_bytes);

  k_transpose_v<<<dim3(8, NH, NB), dim3(256), 0, stream>>>(v, vT);
  k_fuse_softmax<<<dim3(NB * 512), dim3(512), 0, stream>>>(s0, s1, s2, fw, attn);
  k_pv<<<dim3(32, NH, NB), dim3(128), 0, stream>>>(attn, vT, xb);
  k_proj<<<dim3(32, DIM / 64), dim3(256), 0, stream>>>(xb, pw, pb, out);
}